// Round 1
// baseline (177.125 us; speedup 1.0000x reference)
//
#include <hip/hip_runtime.h>
#include <stdint.h>

// ---------------- problem constants ----------------
static constexpr int kH  = 2048;
static constexpr int kW  = 4096;
static constexpr long long kHW = (long long)kH * kW;   // per-channel pixels
static constexpr int kNH = kH / 64;   // 32
static constexpr int kNW = kW / 64;   // 64
static constexpr int kNB = kNH * kNW; // 2048 blocks
static constexpr int kBB = 64 * 64;   // 4096 pixels / block
static constexpr float kGray = 128.0f;

// RNG scheme: 0 = partitionable threefry (JAX >= 0.4.36 default):
//               split: key_i = full cipher(key, (0,i)); bits32 = w0 ^ w1 of cipher(key,(hi(i),lo(i)))
//             1 = legacy iota-halves scheme (flip here if round fails with absmax ~O(100))
#define SCHEME 0

// ---------------- threefry2x32, 20 rounds (matches jax/_src/prng.py) ----------------
__host__ __device__ inline void tf2x32(uint32_t k0, uint32_t k1,
                                       uint32_t x0, uint32_t x1,
                                       uint32_t& o0, uint32_t& o1) {
  uint32_t ks2 = 0x1BD11BDAu ^ k0 ^ k1;
  x0 += k0; x1 += k1;
#define ROTL(v, d) (((v) << (d)) | ((v) >> (32 - (d))))
#define RND(R) { x0 += x1; x1 = ROTL(x1, R); x1 ^= x0; }
  RND(13) RND(15) RND(26) RND(6)
  x0 += k1;  x1 += ks2 + 1u;
  RND(17) RND(29) RND(16) RND(24)
  x0 += ks2; x1 += k0 + 2u;
  RND(13) RND(15) RND(26) RND(6)
  x0 += k0;  x1 += k1 + 3u;
  RND(17) RND(29) RND(16) RND(24)
  x0 += k1;  x1 += ks2 + 4u;
  RND(13) RND(15) RND(26) RND(6)
  x0 += ks2; x1 += k0 + 5u;
  o0 = x0; o1 = x1;
#undef RND
#undef ROTL
}

// random_bits(key, 32, (n,))[idx]
__device__ inline uint32_t rbits(uint32_t ka, uint32_t kb, uint32_t idx, uint32_t n) {
#if SCHEME == 0
  (void)n;
  uint32_t o0, o1;
  tf2x32(ka, kb, 0u, idx, o0, o1);      // hi(i)=0 for all our sizes (< 2^32)
  return o0 ^ o1;
#else
  uint32_t half = n >> 1;
  uint32_t o0, o1;
  if (idx < half) { tf2x32(ka, kb, idx, idx + half, o0, o1); return o0; }
  else            { tf2x32(ka, kb, idx - half, idx, o0, o1); return o1; }
#endif
}

// initial_mask[b] > 0.5  (uniform = bitcast((bits>>9)|0x3f800000)-1, exact: v*2^-23)
__device__ inline bool keep_block(uint32_t k1a, uint32_t k1b, int b) {
  uint32_t v = rbits(k1a, k1b, (uint32_t)b, (uint32_t)kNB) >> 9;
  return v > 0x400000u;   // f > 0.5 exactly
}

// ---------------- K1: per-block depth max + exact serial f32 sums ----------------
__global__ __launch_bounds__(256) void k1_depth(const float* __restrict__ depth,
                                                float* __restrict__ Su,
                                                float* __restrict__ Ss,
                                                float* __restrict__ Bmax,
                                                uint32_t k1a, uint32_t k1b) {
  __shared__ float gu[kBB];       // gray, unscaled
  __shared__ float gs[kBB];       // gray, depth/255 per element (max>1 branch)
  __shared__ float red[256];
  const int b = blockIdx.x, t = threadIdx.x;
  const int bi = b >> 6, bj = b & 63;
  const int y0 = bi * 64, x0 = bj * 64;

  float mx = 0.0f;
  for (int it = 0; it < 16; ++it) {
    int p = it * 256 + t;
    int r = p >> 6, c = p & 63;
    long long a = (long long)(y0 + r) * kW + (x0 + c);
    float d0 = depth[a];
    float d1 = depth[a + kHW];
    float d2 = depth[a + 2 * kHW];
    mx = fmaxf(mx, fmaxf(d0, fmaxf(d1, d2)));
    gu[p] = ((d0 + d1) + d2) / 3.0f;                               // gray_depth pixel
    gs[p] = ((d0 / 255.0f + d1 / 255.0f) + d2 / 255.0f) / 3.0f;    // scaled variant
  }
  red[t] = mx;
  __syncthreads();
  for (int s = 128; s > 0; s >>= 1) {
    if (t < s) red[t] = fmaxf(red[t], red[t + s]);
    __syncthreads();
  }
  if (t == 0) Bmax[b] = red[0];

  // kept blocks never consult num_zeros -> skip the serial chains entirely
  if (keep_block(k1a, k1b, b)) return;

  // exact replication of XLA CPU's sequential f32 reduce (dim1 outer, dim3 inner
  // == row-major pixel order). Lane 0: unscaled; lane 1: scaled. Must NOT be
  // reassociated -- default hipcc FP semantics preserve the chain.
  if (t < 2) {
    const float* g = (t == 0) ? gu : gs;
    float acc = 0.0f;
    for (int p = 0; p < kBB; ++p) acc += g[p];
    if (t == 0) Su[b] = acc; else Ss[b] = acc;
  }
}

// ---------------- K2: global max -> scale flag -> num_zeros per block ----------------
__global__ __launch_bounds__(256) void k2_nz(const float* __restrict__ Su,
                                             const float* __restrict__ Ss,
                                             const float* __restrict__ Bmax,
                                             int* __restrict__ nz,
                                             uint32_t k1a, uint32_t k1b) {
  __shared__ float red[256];
  const int t = threadIdx.x;
  float mx = 0.0f;
  for (int b = t; b < kNB; b += 256) mx = fmaxf(mx, Bmax[b]);
  red[t] = mx;
  __syncthreads();
  for (int s = 128; s > 0; s >>= 1) {
    if (t < s) red[t] = fmaxf(red[t], red[t + s]);
    __syncthreads();
  }
  const bool scaled = red[0] > 1.0f;
  for (int b = t; b < kNB; b += 256) {
    int v;
    if (keep_block(k1a, k1b, b)) {
      v = 0;  // block fully kept -> behaves like zero dropped pixels
    } else {
      float S = scaled ? Ss[b] : Su[b];     // == avg_depth*4096 bit-exactly (pow2 scalings)
      v = (int)rintf(S);                    // round-half-even == jnp.round
      if (v < 0) v = 0;
      if (v > kBB) v = kBB;
    }
    nz[b] = v;
  }
}

// ---------------- K3: noise gen + k-th smallest threshold + masked apply ----------------
__global__ __launch_bounds__(256) void k3_apply(const float* __restrict__ img,
                                                float* __restrict__ out,
                                                const int* __restrict__ nz_arr,
                                                uint32_t k2a, uint32_t k2b) {
  __shared__ uint32_t vals[kBB];   // 23-bit noise mantissas
  __shared__ uint32_t hist[256];
  __shared__ uint32_t cand[kBB];   // worst-case capacity for one top-8 bucket
  __shared__ uint32_t sh[4];       // [0]=bucket, [1]=rank-in-bucket, [2]=threshold key, [3]=cand count
  const int b = blockIdx.x, t = threadIdx.x;
  const int bi = b >> 6, bj = b & 63;
  const int y0 = bi * 64, x0 = bj * 64;
  const int nz = nz_arr[b];

  if (nz == 0) {            // mask == 1 everywhere: out = img
    for (int it = 0; it < 48; ++it) {
      int f = it * 256 + t;
      int c = f >> 12, p = f & 4095, r = p >> 6, cc = p & 63;
      long long a = (long long)c * kHW + (long long)(y0 + r) * kW + (x0 + cc);
      out[a] = img[a];
    }
    return;
  }
  if (nz == kBB) {          // all dropped
    for (int it = 0; it < 48; ++it) {
      int f = it * 256 + t;
      int c = f >> 12, p = f & 4095, r = p >> 6, cc = p & 63;
      long long a = (long long)c * kHW + (long long)(y0 + r) * kW + (x0 + cc);
      out[a] = kGray;
    }
    return;
  }

  for (int i = t; i < 256; i += 256) hist[i] = 0;
  if (t == 0) sh[3] = 0;
  __syncthreads();

  // noise flat index = b*4096 + p over shape (nH, nW, 64*64)
  const uint32_t base = (uint32_t)b * (uint32_t)kBB;
  for (int u = 0; u < 16; ++u) {
    int p = u * 256 + t;
    uint32_t v = rbits(k2a, k2b, base + (uint32_t)p, (uint32_t)(kNB * kBB)) >> 9;
    vals[p] = v;
    atomicAdd(&hist[v >> 15], 1u);
  }
  __syncthreads();

  if (t == 0) {   // find bucket containing the nz-th smallest (1-indexed)
    uint32_t cum = 0;
    for (int i = 0; i < 256; ++i) {
      uint32_t h = hist[i];
      if (cum + h >= (uint32_t)nz) { sh[0] = (uint32_t)i; sh[1] = (uint32_t)nz - cum; break; }
      cum += h;
    }
  }
  __syncthreads();
  const uint32_t Bsel = sh[0], rr = sh[1];

  // collect bucket members as keys (low15bits, pixel-index) -- ties broken by index
  for (int u = 0; u < 16; ++u) {
    int p = u * 256 + t;
    uint32_t v = vals[p];
    if ((v >> 15) == Bsel) {
      uint32_t slot = atomicAdd(&sh[3], 1u);
      cand[slot] = ((v & 0x7FFFu) << 12) | (uint32_t)p;
    }
  }
  __syncthreads();
  const uint32_t m = sh[3];

  // rr-th smallest key (keys are distinct): rank by counting
  for (uint32_t q = t; q < m; q += 256) {
    uint32_t key = cand[q], rank = 0;
    for (uint32_t q2 = 0; q2 < m; ++q2) rank += (cand[q2] < key) ? 1u : 0u;
    if (rank == rr - 1) sh[2] = key;
  }
  __syncthreads();
  const uint32_t T = sh[2];

  for (int it = 0; it < 48; ++it) {
    int f = it * 256 + t;
    int c = f >> 12, p = f & 4095, r = p >> 6, cc = p & 63;
    uint32_t v = vals[p];
    uint32_t top = v >> 15;
    bool zero = (top < Bsel) ||
                (top == Bsel && ((((v & 0x7FFFu) << 12) | (uint32_t)p) <= T));
    long long a = (long long)c * kHW + (long long)(y0 + r) * kW + (x0 + cc);
    out[a] = zero ? kGray : img[a];
  }
}

// ---------------- host ----------------
extern "C" void kernel_launch(void* const* d_in, const int* in_sizes, int n_in,
                              void* d_out, int out_size, void* d_ws, size_t ws_size,
                              hipStream_t stream) {
  const float* img   = (const float*)d_in[0];
  const float* depth = (const float*)d_in[1];
  float* out = (float*)d_out;

  // workspace layout (all fully rewritten every call; poison-safe)
  float* Su   = (float*)d_ws;
  float* Ss   = Su + kNB;
  float* Bmax = Ss + kNB;
  int*   nz   = (int*)(Bmax + kNB);

  // derive split keys on host (pure integer, deterministic)
  uint32_t k1a, k1b, k2a, k2b;
#if SCHEME == 0
  tf2x32(0u, 42u, 0u, 0u, k1a, k1b);   // fold-like split: key_i = cipher(key,(0,i))
  tf2x32(0u, 42u, 0u, 1u, k2a, k2b);
#else
  uint32_t a0, a1, b0, b1;
  tf2x32(0u, 42u, 0u, 2u, a0, a1);     // legacy: counts [0,1,2,3] split in halves
  tf2x32(0u, 42u, 1u, 3u, b0, b1);
  k1a = a0; k1b = b0; k2a = a1; k2b = b1;
#endif

  k1_depth<<<kNB, 256, 0, stream>>>(depth, Su, Ss, Bmax, k1a, k1b);
  k2_nz  <<<1,   256, 0, stream>>>(Su, Ss, Bmax, nz, k1a, k1b);
  k3_apply<<<kNB, 256, 0, stream>>>(img, out, nz, k2a, k2b);
}

// Round 2
// 160.374 us; speedup vs baseline: 1.1044x; 1.1044x over previous
//
#include <hip/hip_runtime.h>
#include <stdint.h>

// ---------------- problem constants ----------------
static constexpr int kH  = 2048;
static constexpr int kW  = 4096;
static constexpr long long kHW = (long long)kH * kW;   // per-channel pixels (2^23)
static constexpr int kNH = kH / 64;   // 32
static constexpr int kNW = kW / 64;   // 64
static constexpr int kNB = kNH * kNW; // 2048 blocks
static constexpr int kBB = 64 * 64;   // 4096 pixels / block
static constexpr int kWordsPerRow = kW / 32;  // 128 bitmap words per image row
static constexpr float kGray = 128.0f;

// partitionable threefry (JAX >= 0.4.36 default) -- validated absmax 0.0 in round 1
__host__ __device__ inline void tf2x32(uint32_t k0, uint32_t k1,
                                       uint32_t x0, uint32_t x1,
                                       uint32_t& o0, uint32_t& o1) {
  uint32_t ks2 = 0x1BD11BDAu ^ k0 ^ k1;
  x0 += k0; x1 += k1;
#define ROTL(v, d) (((v) << (d)) | ((v) >> (32 - (d))))
#define RND(R) { x0 += x1; x1 = ROTL(x1, R); x1 ^= x0; }
  RND(13) RND(15) RND(26) RND(6)
  x0 += k1;  x1 += ks2 + 1u;
  RND(17) RND(29) RND(16) RND(24)
  x0 += ks2; x1 += k0 + 2u;
  RND(13) RND(15) RND(26) RND(6)
  x0 += k0;  x1 += k1 + 3u;
  RND(17) RND(29) RND(16) RND(24)
  x0 += k1;  x1 += ks2 + 4u;
  RND(13) RND(15) RND(26) RND(6)
  x0 += ks2; x1 += k0 + 5u;
  o0 = x0; o1 = x1;
#undef RND
#undef ROTL
}

__device__ inline uint32_t rbits(uint32_t ka, uint32_t kb, uint32_t idx) {
  uint32_t o0, o1;
  tf2x32(ka, kb, 0u, idx, o0, o1);   // hi(counter)=0 for all our sizes
  return o0 ^ o1;
}

__device__ inline bool keep_block(uint32_t k1a, uint32_t k1b, int b) {
  uint32_t v = rbits(k1a, k1b, (uint32_t)b) >> 9;
  return v > 0x400000u;   // uniform > 0.5 exactly
}

// ---------------- K1: per-block depth max + exact serial f32 sums ----------------
__global__ __launch_bounds__(256) void k1_depth(const float* __restrict__ depth,
                                                float* __restrict__ Su,
                                                float* __restrict__ Ss,
                                                float* __restrict__ Bmax,
                                                uint32_t k1a, uint32_t k1b) {
  __shared__ __align__(16) float gu[kBB];   // gray, unscaled
  __shared__ __align__(16) float gs[kBB];   // gray, depth/255 per element
  __shared__ float red[256];
  const int b = blockIdx.x, t = threadIdx.x;
  const int bi = b >> 6, bj = b & 63;
  const int y0 = bi * 64, x0 = bj * 64;
  const bool keep = keep_block(k1a, k1b, b);

  float mx = 0.0f;
  #pragma unroll
  for (int it = 0; it < 4; ++it) {
    int idx = it * 256 + t;           // float4 index in block (1024 total)
    int r = idx >> 4, cq = idx & 15;  // row, col-quad
    long long a = (long long)(y0 + r) * kW + (x0 + cq * 4);
    float4 d0 = *reinterpret_cast<const float4*>(depth + a);
    float4 d1 = *reinterpret_cast<const float4*>(depth + a + kHW);
    float4 d2 = *reinterpret_cast<const float4*>(depth + a + 2 * kHW);
    mx = fmaxf(mx, fmaxf(fmaxf(fmaxf(d0.x, d0.y), fmaxf(d0.z, d0.w)),
               fmaxf(fmaxf(fmaxf(d1.x, d1.y), fmaxf(d1.z, d1.w)),
                     fmaxf(fmaxf(d2.x, d2.y), fmaxf(d2.z, d2.w)))));
    if (!keep) {
      int p = r * 64 + cq * 4;
      gu[p + 0] = ((d0.x + d1.x) + d2.x) / 3.0f;
      gu[p + 1] = ((d0.y + d1.y) + d2.y) / 3.0f;
      gu[p + 2] = ((d0.z + d1.z) + d2.z) / 3.0f;
      gu[p + 3] = ((d0.w + d1.w) + d2.w) / 3.0f;
      gs[p + 0] = ((d0.x / 255.0f + d1.x / 255.0f) + d2.x / 255.0f) / 3.0f;
      gs[p + 1] = ((d0.y / 255.0f + d1.y / 255.0f) + d2.y / 255.0f) / 3.0f;
      gs[p + 2] = ((d0.z / 255.0f + d1.z / 255.0f) + d2.z / 255.0f) / 3.0f;
      gs[p + 3] = ((d0.w / 255.0f + d1.w / 255.0f) + d2.w / 255.0f) / 3.0f;
    }
  }
  red[t] = mx;
  __syncthreads();
  for (int s = 128; s > 0; s >>= 1) {
    if (t < s) red[t] = fmaxf(red[t], red[t + s]);
    __syncthreads();
  }
  if (t == 0) Bmax[b] = red[0];
  if (keep) return;

  // exact sequential f32 chain, hand-pipelined (double-buffered LDS->reg, all
  // static indices). Add ORDER is strictly p=0..4095 -- bit-exact vs XLA CPU.
  if (t < 2) {
    const float* g = (t == 0) ? gu : gs;
    float4 A[8], B[8];
    #pragma unroll
    for (int j = 0; j < 8; ++j) A[j] = *reinterpret_cast<const float4*>(g + 4 * j);
    float acc = 0.0f;
    for (int base = 0; base < kBB; base += 64) {
      #pragma unroll
      for (int j = 0; j < 8; ++j)
        B[j] = *reinterpret_cast<const float4*>(g + base + 32 + 4 * j);
      #pragma unroll
      for (int j = 0; j < 8; ++j) {
        acc += A[j].x; acc += A[j].y; acc += A[j].z; acc += A[j].w;
      }
      if (base + 64 < kBB) {
        #pragma unroll
        for (int j = 0; j < 8; ++j)
          A[j] = *reinterpret_cast<const float4*>(g + base + 64 + 4 * j);
      }
      #pragma unroll
      for (int j = 0; j < 8; ++j) {
        acc += B[j].x; acc += B[j].y; acc += B[j].z; acc += B[j].w;
      }
    }
    if (t == 0) Su[b] = acc; else Ss[b] = acc;
  }
}

// ---------------- K2: global max -> scale flag -> num_zeros per block ----------------
__global__ __launch_bounds__(256) void k2_nz(const float* __restrict__ Su,
                                             const float* __restrict__ Ss,
                                             const float* __restrict__ Bmax,
                                             int* __restrict__ nz,
                                             uint32_t k1a, uint32_t k1b) {
  __shared__ float red[256];
  const int t = threadIdx.x;
  float mx = 0.0f;
  for (int b = t; b < kNB; b += 256) mx = fmaxf(mx, Bmax[b]);
  red[t] = mx;
  __syncthreads();
  for (int s = 128; s > 0; s >>= 1) {
    if (t < s) red[t] = fmaxf(red[t], red[t + s]);
    __syncthreads();
  }
  const bool scaled = red[0] > 1.0f;
  for (int b = t; b < kNB; b += 256) {
    int v;
    if (keep_block(k1a, k1b, b)) {
      v = 0;
    } else {
      float S = scaled ? Ss[b] : Su[b];   // == avg_depth*4096 bit-exactly
      v = (int)rintf(S);                  // round-half-even == jnp.round
      if (v < 0) v = 0;
      if (v > kBB) v = kBB;
    }
    nz[b] = v;
  }
}

// ---------------- K3a: noise gen + threshold select -> full-res bitmap ----------------
__global__ __launch_bounds__(256) void k3a_mask(const int* __restrict__ nz_arr,
                                                uint32_t* __restrict__ bm,
                                                uint32_t k2a, uint32_t k2b) {
  __shared__ uint32_t vals[kBB];
  __shared__ uint32_t hist[256];
  __shared__ uint32_t cand[kBB];
  __shared__ uint32_t sh[4];
  const int b = blockIdx.x, t = threadIdx.x;
  const int bi = b >> 6, bj = b & 63;
  const int y0 = bi * 64;
  const int wx = bj * 2;            // word-column base (x0>>5)
  const int nz = nz_arr[b];

  if (nz == 0 || nz == kBB) {       // uniform block: all-keep or all-drop
    const uint32_t fill = (nz == 0) ? 0xFFFFFFFFu : 0u;
    if (t < 128) {                  // word w: row t>>1, half t&1
      bm[(y0 + (t >> 1)) * kWordsPerRow + wx + (t & 1)] = fill;
    }
    return;
  }

  for (int i = t; i < 256; i += 256) hist[i] = 0;
  if (t == 0) sh[3] = 0;
  __syncthreads();

  const uint32_t base = (uint32_t)b * (uint32_t)kBB;
  #pragma unroll
  for (int u = 0; u < 16; ++u) {
    int p = u * 256 + t;
    uint32_t v = rbits(k2a, k2b, base + (uint32_t)p) >> 9;
    vals[p] = v;
    atomicAdd(&hist[v >> 15], 1u);
  }
  __syncthreads();

  if (t == 0) {   // bucket containing the nz-th smallest (1-indexed)
    uint32_t cum = 0;
    for (int i = 0; i < 256; ++i) {
      uint32_t h = hist[i];
      if (cum + h >= (uint32_t)nz) { sh[0] = (uint32_t)i; sh[1] = (uint32_t)nz - cum; break; }
      cum += h;
    }
  }
  __syncthreads();
  const uint32_t Bsel = sh[0], rr = sh[1];

  #pragma unroll
  for (int u = 0; u < 16; ++u) {
    int p = u * 256 + t;
    uint32_t v = vals[p];
    if ((v >> 15) == Bsel) {
      uint32_t slot = atomicAdd(&sh[3], 1u);
      cand[slot] = ((v & 0x7FFFu) << 12) | (uint32_t)p;
    }
  }
  __syncthreads();
  const uint32_t m = sh[3];

  for (uint32_t q = t; q < m; q += 256) {   // rr-th smallest key (keys distinct)
    uint32_t key = cand[q], rank = 0;
    for (uint32_t q2 = 0; q2 < m; ++q2) rank += (cand[q2] < key) ? 1u : 0u;
    if (rank == rr - 1) sh[2] = key;
  }
  __syncthreads();
  const uint32_t T = sh[2];

  // emit bitmap: bit=1 -> keep pixel. ballot packs 64 lanes -> 2 words.
  #pragma unroll
  for (int k = 0; k < 16; ++k) {
    int p = k * 256 + t;
    uint32_t v = vals[p];
    uint32_t top = v >> 15;
    bool zero = (top < Bsel) ||
                (top == Bsel && ((((v & 0x7FFFu) << 12) | (uint32_t)p) <= T));
    unsigned long long mball = __ballot(!zero);
    int lane = t & 63;
    if (lane == 0 || lane == 32) {
      uint32_t w = (lane == 0) ? (uint32_t)mball : (uint32_t)(mball >> 32);
      // word for this lane's own p: row p>>6, half (p>>5)&1
      bm[(y0 + (p >> 6)) * kWordsPerRow + wx + ((p >> 5) & 1)] = w;
    }
  }
}

// ---------------- K3b: pure streaming apply ----------------
__global__ __launch_bounds__(256) void k3b_apply(const float* __restrict__ img,
                                                 const uint32_t* __restrict__ bm,
                                                 float* __restrict__ out) {
  const int tid = blockIdx.x * 256 + threadIdx.x;   // 524288 threads
  #pragma unroll
  for (int it = 0; it < 12; ++it) {
    long long f4 = (long long)it * 524288 + tid;
    long long e = f4 * 4;
    int q = (int)(e & (kHW - 1));                   // pixel index within channel
    uint32_t w = bm[q >> 5];
    uint32_t s = (uint32_t)(q & 31);                // multiple of 4
    float4 v = *reinterpret_cast<const float4*>(img + e);
    float4 o;
    o.x = ((w >> (s + 0)) & 1u) ? v.x : kGray;
    o.y = ((w >> (s + 1)) & 1u) ? v.y : kGray;
    o.z = ((w >> (s + 2)) & 1u) ? v.z : kGray;
    o.w = ((w >> (s + 3)) & 1u) ? v.w : kGray;
    *reinterpret_cast<float4*>(out + e) = o;
  }
}

// ---------------- host ----------------
extern "C" void kernel_launch(void* const* d_in, const int* in_sizes, int n_in,
                              void* d_out, int out_size, void* d_ws, size_t ws_size,
                              hipStream_t stream) {
  const float* img   = (const float*)d_in[0];
  const float* depth = (const float*)d_in[1];
  float* out = (float*)d_out;

  // workspace layout (~1.03 MB, fully rewritten every call)
  uint32_t* bm = (uint32_t*)d_ws;               // kH*kW/32 = 262144 words
  float* Su   = (float*)(bm + kH * kW / 32);
  float* Ss   = Su + kNB;
  float* Bmax = Ss + kNB;
  int*   nz   = (int*)(Bmax + kNB);

  uint32_t k1a, k1b, k2a, k2b;
  tf2x32(0u, 42u, 0u, 0u, k1a, k1b);   // split(key(42))[0]
  tf2x32(0u, 42u, 0u, 1u, k2a, k2b);   // split(key(42))[1]

  k1_depth<<<kNB, 256, 0, stream>>>(depth, Su, Ss, Bmax, k1a, k1b);
  k2_nz   <<<1,   256, 0, stream>>>(Su, Ss, Bmax, nz, k1a, k1b);
  k3a_mask<<<kNB, 256, 0, stream>>>(nz, bm, k2a, k2b);
  k3b_apply<<<2048, 256, 0, stream>>>(img, bm, out);
}

// Round 3
// 152.972 us; speedup vs baseline: 1.1579x; 1.0484x over previous
//
#include <hip/hip_runtime.h>
#include <stdint.h>

// ---------------- problem constants ----------------
static constexpr int kH  = 2048;
static constexpr int kW  = 4096;
static constexpr long long kHW = (long long)kH * kW;   // per-channel pixels (2^23)
static constexpr int kNH = kH / 64;   // 32
static constexpr int kNW = kW / 64;   // 64
static constexpr int kNB = kNH * kNW; // 2048 blocks
static constexpr int kBB = 64 * 64;   // 4096 pixels / block
static constexpr int kWordsPerRow = kW / 32;  // 128 bitmap words per image row
static constexpr long long kGrayN = (long long)kNB * kBB;  // 8388608 floats / variant
static constexpr float kGray = 128.0f;

// partitionable threefry (JAX >= 0.4.36 default) -- validated absmax 0.0 in rounds 1-2
__host__ __device__ inline void tf2x32(uint32_t k0, uint32_t k1,
                                       uint32_t x0, uint32_t x1,
                                       uint32_t& o0, uint32_t& o1) {
  uint32_t ks2 = 0x1BD11BDAu ^ k0 ^ k1;
  x0 += k0; x1 += k1;
#define ROTL(v, d) (((v) << (d)) | ((v) >> (32 - (d))))
#define RND(R) { x0 += x1; x1 = ROTL(x1, R); x1 ^= x0; }
  RND(13) RND(15) RND(26) RND(6)
  x0 += k1;  x1 += ks2 + 1u;
  RND(17) RND(29) RND(16) RND(24)
  x0 += ks2; x1 += k0 + 2u;
  RND(13) RND(15) RND(26) RND(6)
  x0 += k0;  x1 += k1 + 3u;
  RND(17) RND(29) RND(16) RND(24)
  x0 += k1;  x1 += ks2 + 4u;
  RND(13) RND(15) RND(26) RND(6)
  x0 += ks2; x1 += k0 + 5u;
  o0 = x0; o1 = x1;
#undef RND
#undef ROTL
}

__device__ inline uint32_t rbits(uint32_t ka, uint32_t kb, uint32_t idx) {
  uint32_t o0, o1;
  tf2x32(ka, kb, 0u, idx, o0, o1);   // hi(counter)=0 for all our sizes
  return o0 ^ o1;
}

__device__ inline bool keep_block(uint32_t k1a, uint32_t k1b, int b) {
  uint32_t v = rbits(k1a, k1b, (uint32_t)b) >> 9;
  return v > 0x400000u;   // uniform > 0.5 exactly
}

// ---------------- K1: streaming — block max + gray (both variants) for dropped ----------------
__global__ __launch_bounds__(256) void k1_depth(const float* __restrict__ depth,
                                                float* __restrict__ Gu,
                                                float* __restrict__ Gs,
                                                float* __restrict__ Bmax,
                                                uint32_t k1a, uint32_t k1b_) {
  __shared__ float red[256];
  const int b = blockIdx.x, t = threadIdx.x;
  const int bi = b >> 6, bj = b & 63;
  const int y0 = bi * 64, x0 = bj * 64;
  const bool keep = keep_block(k1a, k1b_, b);

  float mx = 0.0f;
  #pragma unroll
  for (int it = 0; it < 4; ++it) {
    int idx = it * 256 + t;           // float4 index in block (1024 total)
    int r = idx >> 4, cq = idx & 15;  // row, col-quad
    long long a = (long long)(y0 + r) * kW + (x0 + cq * 4);
    float4 d0 = *reinterpret_cast<const float4*>(depth + a);
    float4 d1 = *reinterpret_cast<const float4*>(depth + a + kHW);
    float4 d2 = *reinterpret_cast<const float4*>(depth + a + 2 * kHW);
    mx = fmaxf(mx, fmaxf(fmaxf(fmaxf(d0.x, d0.y), fmaxf(d0.z, d0.w)),
               fmaxf(fmaxf(fmaxf(d1.x, d1.y), fmaxf(d1.z, d1.w)),
                     fmaxf(fmaxf(d2.x, d2.y), fmaxf(d2.z, d2.w)))));
    if (!keep) {
      long long p = (long long)b * kBB + (long long)idx * 4;   // p == r*64 + cq*4
      float4 u, s;
      u.x = ((d0.x + d1.x) + d2.x) / 3.0f;
      u.y = ((d0.y + d1.y) + d2.y) / 3.0f;
      u.z = ((d0.z + d1.z) + d2.z) / 3.0f;
      u.w = ((d0.w + d1.w) + d2.w) / 3.0f;
      s.x = ((d0.x / 255.0f + d1.x / 255.0f) + d2.x / 255.0f) / 3.0f;
      s.y = ((d0.y / 255.0f + d1.y / 255.0f) + d2.y / 255.0f) / 3.0f;
      s.z = ((d0.z / 255.0f + d1.z / 255.0f) + d2.z / 255.0f) / 3.0f;
      s.w = ((d0.w / 255.0f + d1.w / 255.0f) + d2.w / 255.0f) / 3.0f;
      *reinterpret_cast<float4*>(Gu + p) = u;
      *reinterpret_cast<float4*>(Gs + p) = s;
    }
  }
  red[t] = mx;
  __syncthreads();
  for (int s = 128; s > 0; s >>= 1) {
    if (t < s) red[t] = fmaxf(red[t], red[t + s]);
    __syncthreads();
  }
  if (t == 0) Bmax[b] = red[0];
}

// ---------------- k1b: flag + deterministic compact dropped list (1 WG) ----------------
__global__ __launch_bounds__(256) void k1b_meta(const float* __restrict__ Bmax,
                                                int* __restrict__ meta,
                                                int* __restrict__ list,
                                                uint32_t k1a, uint32_t k1b_) {
  __shared__ float red[256];
  __shared__ int cnt[256];
  __shared__ uint8_t kb[kNB];
  const int t = threadIdx.x;

  float mx = 0.0f;
  for (int b = t; b < kNB; b += 256) mx = fmaxf(mx, Bmax[b]);
  red[t] = mx;
  __syncthreads();
  for (int s = 128; s > 0; s >>= 1) {
    if (t < s) red[t] = fmaxf(red[t], red[t + s]);
    __syncthreads();
  }
  if (t == 0) meta[1] = (red[0] > 1.0f) ? 1 : 0;

  int c = 0;
  #pragma unroll
  for (int j = 0; j < 8; ++j) {
    int b = t * 8 + j;
    bool k = keep_block(k1a, k1b_, b);
    kb[b] = k ? 1 : 0;
    c += k ? 0 : 1;
  }
  cnt[t] = c;
  __syncthreads();
  // inclusive Hillis-Steele scan (deterministic)
  for (int s = 1; s < 256; s <<= 1) {
    int v = (t >= s) ? cnt[t - s] : 0;
    __syncthreads();
    cnt[t] += v;
    __syncthreads();
  }
  int off = cnt[t] - c;   // exclusive prefix
  #pragma unroll
  for (int j = 0; j < 8; ++j) {
    int b = t * 8 + j;
    if (!kb[b]) list[off++] = b;
  }
  if (t == 255) meta[0] = cnt[255];   // dropped count
}

// ---------------- kchain: exact serial sums, 2 chains/wave, 32-deep reg pipeline ----------------
__global__ __launch_bounds__(64) void kchain(const float* __restrict__ G,
                                             const int* __restrict__ meta,
                                             const int* __restrict__ list,
                                             float* __restrict__ S) {
  const int w = blockIdx.x, lane = threadIdx.x;
  const int count = meta[0];
  const int base2 = w * 2;
  if (base2 >= count) return;
  const int flag = meta[1];

  if (lane < 2) {
    const int ci = base2 + lane;
    const bool act = ci < count;
    const int blk = list[act ? ci : base2];
    const float* g = G + (flag ? kGrayN : 0) + (long long)blk * kBB;

    float4 buf[32];
    #pragma unroll
    for (int i = 0; i < 32; ++i)
      buf[i] = *reinterpret_cast<const float4*>(g + 4 * i);
    const float* gp = g + 128;

    float acc = 0.0f;
    for (int outer = 0; outer < 31; ++outer) {
      #pragma unroll
      for (int i = 0; i < 32; ++i) {
        float4 v = buf[i];
        buf[i] = *reinterpret_cast<const float4*>(gp);
        gp += 4;
        acc += v.x; acc += v.y; acc += v.z; acc += v.w;   // strict order p=0..4095
      }
    }
    #pragma unroll
    for (int i = 0; i < 32; ++i) {
      float4 v = buf[i];
      acc += v.x; acc += v.y; acc += v.z; acc += v.w;
    }
    if (act) S[blk] = acc;
  }
}

// ---------------- k2: num_zeros per block ----------------
__global__ __launch_bounds__(256) void k2_nz(const float* __restrict__ S,
                                             int* __restrict__ nz,
                                             uint32_t k1a, uint32_t k1b_) {
  const int b = blockIdx.x * 256 + threadIdx.x;
  if (b >= kNB) return;
  int v;
  if (keep_block(k1a, k1b_, b)) {
    v = 0;
  } else {
    float s = S[b];              // == avg_depth*4096 bit-exactly (pow2 scalings)
    v = (int)rintf(s);           // round-half-even == jnp.round
    if (v < 0) v = 0;
    if (v > kBB) v = kBB;
  }
  nz[b] = v;
}

// ---------------- K3a: noise gen + threshold select -> full-res bitmap ----------------
__global__ __launch_bounds__(256) void k3a_mask(const int* __restrict__ nz_arr,
                                                uint32_t* __restrict__ bm,
                                                uint32_t k2a, uint32_t k2b) {
  __shared__ uint32_t vals[kBB];
  __shared__ uint32_t hist[256];
  __shared__ uint32_t cand[kBB];
  __shared__ uint32_t sh[4];
  const int b = blockIdx.x, t = threadIdx.x;
  const int bi = b >> 6, bj = b & 63;
  const int y0 = bi * 64;
  const int wx = bj * 2;            // word-column base (x0>>5)
  const int nz = nz_arr[b];

  if (nz == 0 || nz == kBB) {       // uniform block: all-keep or all-drop
    const uint32_t fill = (nz == 0) ? 0xFFFFFFFFu : 0u;
    if (t < 128) {                  // word w: row t>>1, half t&1
      bm[(y0 + (t >> 1)) * kWordsPerRow + wx + (t & 1)] = fill;
    }
    return;
  }

  for (int i = t; i < 256; i += 256) hist[i] = 0;
  if (t == 0) sh[3] = 0;
  __syncthreads();

  const uint32_t base = (uint32_t)b * (uint32_t)kBB;
  #pragma unroll
  for (int u = 0; u < 16; ++u) {
    int p = u * 256 + t;
    uint32_t v = rbits(k2a, k2b, base + (uint32_t)p) >> 9;
    vals[p] = v;
    atomicAdd(&hist[v >> 15], 1u);
  }
  __syncthreads();

  if (t == 0) {   // bucket containing the nz-th smallest (1-indexed)
    uint32_t cum = 0;
    for (int i = 0; i < 256; ++i) {
      uint32_t h = hist[i];
      if (cum + h >= (uint32_t)nz) { sh[0] = (uint32_t)i; sh[1] = (uint32_t)nz - cum; break; }
      cum += h;
    }
  }
  __syncthreads();
  const uint32_t Bsel = sh[0], rr = sh[1];

  #pragma unroll
  for (int u = 0; u < 16; ++u) {
    int p = u * 256 + t;
    uint32_t v = vals[p];
    if ((v >> 15) == Bsel) {
      uint32_t slot = atomicAdd(&sh[3], 1u);
      cand[slot] = ((v & 0x7FFFu) << 12) | (uint32_t)p;
    }
  }
  __syncthreads();
  const uint32_t m = sh[3];

  for (uint32_t q = t; q < m; q += 256) {   // rr-th smallest key (keys distinct)
    uint32_t key = cand[q], rank = 0;
    for (uint32_t q2 = 0; q2 < m; ++q2) rank += (cand[q2] < key) ? 1u : 0u;
    if (rank == rr - 1) sh[2] = key;
  }
  __syncthreads();
  const uint32_t T = sh[2];

  // emit bitmap: bit=1 -> keep pixel. ballot packs 64 lanes -> 2 words.
  #pragma unroll
  for (int k = 0; k < 16; ++k) {
    int p = k * 256 + t;
    uint32_t v = vals[p];
    uint32_t top = v >> 15;
    bool zero = (top < Bsel) ||
                (top == Bsel && ((((v & 0x7FFFu) << 12) | (uint32_t)p) <= T));
    unsigned long long mball = __ballot(!zero);
    int lane = t & 63;
    if (lane == 0 || lane == 32) {
      uint32_t w = (lane == 0) ? (uint32_t)mball : (uint32_t)(mball >> 32);
      bm[(y0 + (p >> 6)) * kWordsPerRow + wx + ((p >> 5) & 1)] = w;
    }
  }
}

// ---------------- K3b: pure streaming apply ----------------
__global__ __launch_bounds__(256) void k3b_apply(const float* __restrict__ img,
                                                 const uint32_t* __restrict__ bm,
                                                 float* __restrict__ out) {
  const int tid = blockIdx.x * 256 + threadIdx.x;   // 524288 threads
  #pragma unroll
  for (int it = 0; it < 12; ++it) {
    long long f4 = (long long)it * 524288 + tid;
    long long e = f4 * 4;
    int q = (int)(e & (kHW - 1));                   // pixel index within channel
    uint32_t w = bm[q >> 5];
    uint32_t s = (uint32_t)(q & 31);                // multiple of 4
    float4 v = *reinterpret_cast<const float4*>(img + e);
    float4 o;
    o.x = ((w >> (s + 0)) & 1u) ? v.x : kGray;
    o.y = ((w >> (s + 1)) & 1u) ? v.y : kGray;
    o.z = ((w >> (s + 2)) & 1u) ? v.z : kGray;
    o.w = ((w >> (s + 3)) & 1u) ? v.w : kGray;
    *reinterpret_cast<float4*>(out + e) = o;
  }
}

// ---------------- host ----------------
extern "C" void kernel_launch(void* const* d_in, const int* in_sizes, int n_in,
                              void* d_out, int out_size, void* d_ws, size_t ws_size,
                              hipStream_t stream) {
  const float* img   = (const float*)d_in[0];
  const float* depth = (const float*)d_in[1];
  float* out = (float*)d_out;

  // gray scratch lives in d_out (100 MB; fully overwritten by k3b afterwards)
  float* Gu = out;                       // [kNB][4096], dropped blocks only
  float* Gs = out + kGrayN;              // second variant

  // d_ws layout (~1.04 MB, rewritten every call)
  uint32_t* bm = (uint32_t*)d_ws;        // kH*kW/32 = 262144 words
  float* S    = (float*)(bm + kH * kW / 32);
  float* Bmax = S + kNB;
  int*   nz   = (int*)(Bmax + kNB);
  int*   meta = nz + kNB;                // [0]=dropped count, [1]=scaled flag
  int*   list = meta + 8;                // compact dropped-block ids (<=2048)

  uint32_t k1a, k1b_, k2a, k2b;
  tf2x32(0u, 42u, 0u, 0u, k1a, k1b_);    // split(key(42))[0]
  tf2x32(0u, 42u, 0u, 1u, k2a, k2b);     // split(key(42))[1]

  k1_depth<<<kNB, 256, 0, stream>>>(depth, Gu, Gs, Bmax, k1a, k1b_);
  k1b_meta<<<1, 256, 0, stream>>>(Bmax, meta, list, k1a, k1b_);
  kchain  <<<kNB / 2, 64, 0, stream>>>(out, meta, list, S);
  k2_nz   <<<(kNB + 255) / 256, 256, 0, stream>>>(S, nz, k1a, k1b_);
  k3a_mask<<<kNB, 256, 0, stream>>>(nz, bm, k2a, k2b);
  k3b_apply<<<2048, 256, 0, stream>>>(img, bm, out);
}

// Round 5
// 145.728 us; speedup vs baseline: 1.2154x; 1.0497x over previous
//
#include <hip/hip_runtime.h>
#include <stdint.h>

// ---------------- problem constants ----------------
static constexpr int kH  = 2048;
static constexpr int kW  = 4096;
static constexpr int kHW = kH * kW;            // per-channel pixels (2^23, fits int)
static constexpr int kNH = kH / 64;   // 32
static constexpr int kNW = kW / 64;   // 64
static constexpr int kNB = kNH * kNW; // 2048 blocks
static constexpr int kBB = 64 * 64;   // 4096 pixels / block
static constexpr int kWordsPerRow = kW / 32;   // 128 bitmap words per image row
static constexpr int kGrayN = kNB * kBB;       // 8388608 floats / variant
static constexpr float kGray = 128.0f;

typedef float f32x4 __attribute__((ext_vector_type(4)));

__device__ inline void nt_store4(const float4& v, float* p) {
  f32x4 x;
  x.x = v.x; x.y = v.y; x.z = v.z; x.w = v.w;
  __builtin_nontemporal_store(x, reinterpret_cast<f32x4*>(p));
}

// partitionable threefry (JAX >= 0.4.36 default) -- validated absmax 0.0 rounds 1-3
__host__ __device__ inline void tf2x32(uint32_t k0, uint32_t k1,
                                       uint32_t x0, uint32_t x1,
                                       uint32_t& o0, uint32_t& o1) {
  uint32_t ks2 = 0x1BD11BDAu ^ k0 ^ k1;
  x0 += k0; x1 += k1;
#define ROTL(v, d) (((v) << (d)) | ((v) >> (32 - (d))))
#define RND(R) { x0 += x1; x1 = ROTL(x1, R); x1 ^= x0; }
  RND(13) RND(15) RND(26) RND(6)
  x0 += k1;  x1 += ks2 + 1u;
  RND(17) RND(29) RND(16) RND(24)
  x0 += ks2; x1 += k0 + 2u;
  RND(13) RND(15) RND(26) RND(6)
  x0 += k0;  x1 += k1 + 3u;
  RND(17) RND(29) RND(16) RND(24)
  x0 += k1;  x1 += ks2 + 4u;
  RND(13) RND(15) RND(26) RND(6)
  x0 += ks2; x1 += k0 + 5u;
  o0 = x0; o1 = x1;
#undef RND
#undef ROTL
}

__device__ inline uint32_t rbits(uint32_t ka, uint32_t kb, uint32_t idx) {
  uint32_t o0, o1;
  tf2x32(ka, kb, 0u, idx, o0, o1);   // hi(counter)=0 for all our sizes
  return o0 ^ o1;
}

__device__ inline bool keep_block(uint32_t k1a, uint32_t k1b, int b) {
  uint32_t v = rbits(k1a, k1b, (uint32_t)b) >> 9;
  return v > 0x400000u;   // uniform > 0.5 exactly
}

// ---------------- K1: streaming — block max + gray (both variants) for dropped ----------------
__global__ __launch_bounds__(256) void k1_depth(const float* __restrict__ depth,
                                                float* __restrict__ Gu,
                                                float* __restrict__ Gs,
                                                float* __restrict__ Bmax,
                                                uint32_t k1a, uint32_t k1b_) {
  __shared__ float red[256];
  const int b = blockIdx.x, t = threadIdx.x;
  const int bi = b >> 6, bj = b & 63;
  const int y0 = bi * 64, x0 = bj * 64;
  const bool keep = keep_block(k1a, k1b_, b);
  const float4* d4 = reinterpret_cast<const float4*>(depth);

  float mx = 0.0f;
  #pragma unroll
  for (int it = 0; it < 4; ++it) {
    int idx = it * 256 + t;              // float4 index in block (1024 total)
    int r = idx >> 4, cq = idx & 15;     // row, col-quad
    uint32_t a4 = (uint32_t)(y0 + r) * (kW / 4) + (uint32_t)(x0 / 4 + cq);
    float4 d0 = d4[a4];
    float4 d1 = d4[a4 + kHW / 4];
    float4 d2 = d4[a4 + 2 * (kHW / 4)];
    mx = fmaxf(mx, fmaxf(fmaxf(fmaxf(d0.x, d0.y), fmaxf(d0.z, d0.w)),
               fmaxf(fmaxf(fmaxf(d1.x, d1.y), fmaxf(d1.z, d1.w)),
                     fmaxf(fmaxf(d2.x, d2.y), fmaxf(d2.z, d2.w)))));
    if (!keep) {
      uint32_t p = (uint32_t)b * kBB + (uint32_t)idx * 4u;   // element offset
      float4 u, s;
      u.x = ((d0.x + d1.x) + d2.x) / 3.0f;
      u.y = ((d0.y + d1.y) + d2.y) / 3.0f;
      u.z = ((d0.z + d1.z) + d2.z) / 3.0f;
      u.w = ((d0.w + d1.w) + d2.w) / 3.0f;
      s.x = ((d0.x / 255.0f + d1.x / 255.0f) + d2.x / 255.0f) / 3.0f;
      s.y = ((d0.y / 255.0f + d1.y / 255.0f) + d2.y / 255.0f) / 3.0f;
      s.z = ((d0.z / 255.0f + d1.z / 255.0f) + d2.z / 255.0f) / 3.0f;
      s.w = ((d0.w / 255.0f + d1.w / 255.0f) + d2.w / 255.0f) / 3.0f;
      nt_store4(u, Gu + p);
      nt_store4(s, Gs + p);
    }
  }
  red[t] = mx;
  __syncthreads();
  for (int s = 128; s > 0; s >>= 1) {
    if (t < s) red[t] = fmaxf(red[t], red[t + s]);
    __syncthreads();
  }
  if (t == 0) Bmax[b] = red[0];
}

// ---------------- k1b: flag + deterministic compact dropped list (1 WG) ----------------
__global__ __launch_bounds__(256) void k1b_meta(const float* __restrict__ Bmax,
                                                int* __restrict__ meta,
                                                int* __restrict__ list,
                                                uint32_t k1a, uint32_t k1b_) {
  __shared__ float red[256];
  __shared__ int cnt[256];
  __shared__ uint8_t kb[kNB];
  const int t = threadIdx.x;

  float mx = 0.0f;
  for (int b = t; b < kNB; b += 256) mx = fmaxf(mx, Bmax[b]);
  red[t] = mx;
  __syncthreads();
  for (int s = 128; s > 0; s >>= 1) {
    if (t < s) red[t] = fmaxf(red[t], red[t + s]);
    __syncthreads();
  }
  if (t == 0) meta[1] = (red[0] > 1.0f) ? 1 : 0;

  int c = 0;
  #pragma unroll
  for (int j = 0; j < 8; ++j) {
    int b = t * 8 + j;
    bool k = keep_block(k1a, k1b_, b);
    kb[b] = k ? 1 : 0;
    c += k ? 0 : 1;
  }
  cnt[t] = c;
  __syncthreads();
  for (int s = 1; s < 256; s <<= 1) {   // inclusive Hillis-Steele scan
    int v = (t >= s) ? cnt[t - s] : 0;
    __syncthreads();
    cnt[t] += v;
    __syncthreads();
  }
  int off = cnt[t] - c;                 // exclusive prefix
  #pragma unroll
  for (int j = 0; j < 8; ++j) {
    int b = t * 8 + j;
    if (!kb[b]) list[off++] = b;
  }
  if (t == 255) meta[0] = cnt[255];     // dropped count
}

// ---------------- kchain: exact serial sums, 2 chains/wave, 32-deep reg pipeline ----------------
__global__ __launch_bounds__(64) void kchain(const float* __restrict__ G,
                                             const int* __restrict__ meta,
                                             const int* __restrict__ list,
                                             float* __restrict__ S) {
  const int w = blockIdx.x, lane = threadIdx.x;
  const int count = meta[0];
  const int base2 = w * 2;
  if (base2 >= count) return;
  const int flag = meta[1];

  if (lane < 2) {
    const int ci = base2 + lane;
    const bool act = ci < count;
    const int blk = list[act ? ci : base2];
    const float4* g4 = reinterpret_cast<const float4*>(G) +
                       (flag ? (uint32_t)(kGrayN / 4) : 0u) + (uint32_t)blk * (kBB / 4);

    float4 buf[32];
    #pragma unroll
    for (int i = 0; i < 32; ++i) buf[i] = g4[i];
    uint32_t gp = 32;

    float acc = 0.0f;
    for (int outer = 0; outer < 31; ++outer) {
      #pragma unroll
      for (int i = 0; i < 32; ++i) {
        float4 v = buf[i];
        buf[i] = g4[gp + i];
        acc += v.x; acc += v.y; acc += v.z; acc += v.w;   // strict order p=0..4095
      }
      gp += 32;
    }
    #pragma unroll
    for (int i = 0; i < 32; ++i) {
      float4 v = buf[i];
      acc += v.x; acc += v.y; acc += v.z; acc += v.w;
    }
    if (act) S[blk] = acc;
  }
}

// ---------------- K3a: nz inline + noise + threshold select -> full-res bitmap ----------------
__global__ __launch_bounds__(256) void k3a_mask(const float* __restrict__ S,
                                               uint32_t* __restrict__ bm,
                                               uint32_t k1a, uint32_t k1b_,
                                               uint32_t k2a, uint32_t k2b) {
  __shared__ uint32_t vals[kBB];
  __shared__ uint32_t hist[256];
  __shared__ uint32_t cand[kBB];
  __shared__ uint32_t sh[4];
  const int b = blockIdx.x, t = threadIdx.x;
  const int bi = b >> 6, bj = b & 63;
  const int y0 = bi * 64;
  const int wx = bj * 2;               // word-column base (x0>>5)

  // --- folded k2: num_zeros for this block ---
  int nz;
  if (keep_block(k1a, k1b_, b)) {
    nz = 0;
  } else {
    float s = S[b];                    // == avg_depth*4096 bit-exactly (pow2 scalings)
    nz = (int)rintf(s);                // round-half-even == jnp.round
    if (nz < 0) nz = 0;
    if (nz > kBB) nz = kBB;
  }

  if (nz == 0 || nz == kBB) {          // uniform block: all-keep or all-drop
    const uint32_t fill = (nz == 0) ? 0xFFFFFFFFu : 0u;
    if (t < 128) {                     // word: row t>>1, half t&1
      bm[(y0 + (t >> 1)) * kWordsPerRow + wx + (t & 1)] = fill;
    }
    return;
  }

  for (int i = t; i < 256; i += 256) hist[i] = 0;
  if (t == 0) sh[3] = 0;
  __syncthreads();

  const uint32_t base = (uint32_t)b * (uint32_t)kBB;
  #pragma unroll
  for (int u = 0; u < 16; ++u) {
    int p = u * 256 + t;
    uint32_t v = rbits(k2a, k2b, base + (uint32_t)p) >> 9;
    vals[p] = v;
    atomicAdd(&hist[v >> 15], 1u);
  }
  __syncthreads();

  if (t == 0) {                        // bucket containing the nz-th smallest (1-indexed)
    uint32_t cum = 0;
    for (int i = 0; i < 256; ++i) {
      uint32_t h = hist[i];
      if (cum + h >= (uint32_t)nz) { sh[0] = (uint32_t)i; sh[1] = (uint32_t)nz - cum; break; }
      cum += h;
    }
  }
  __syncthreads();
  const uint32_t Bsel = sh[0], rr = sh[1];

  #pragma unroll
  for (int u = 0; u < 16; ++u) {
    int p = u * 256 + t;
    uint32_t v = vals[p];
    if ((v >> 15) == Bsel) {
      uint32_t slot = atomicAdd(&sh[3], 1u);
      cand[slot] = ((v & 0x7FFFu) << 12) | (uint32_t)p;
    }
  }
  __syncthreads();
  const uint32_t m = sh[3];

  for (uint32_t q = t; q < m; q += 256) {   // rr-th smallest key (keys distinct)
    uint32_t key = cand[q], rank = 0;
    for (uint32_t q2 = 0; q2 < m; ++q2) rank += (cand[q2] < key) ? 1u : 0u;
    if (rank == rr - 1) sh[2] = key;
  }
  __syncthreads();
  const uint32_t T = sh[2];

  // emit bitmap: bit=1 -> keep pixel. ballot packs 64 lanes -> 2 words.
  #pragma unroll
  for (int k = 0; k < 16; ++k) {
    int p = k * 256 + t;
    uint32_t v = vals[p];
    uint32_t top = v >> 15;
    bool zero = (top < Bsel) ||
                (top == Bsel && ((((v & 0x7FFFu) << 12) | (uint32_t)p) <= T));
    unsigned long long mball = __ballot(!zero);
    int lane = t & 63;
    if (lane == 0 || lane == 32) {
      uint32_t w = (lane == 0) ? (uint32_t)mball : (uint32_t)(mball >> 32);
      bm[(y0 + (p >> 6)) * kWordsPerRow + wx + ((p >> 5) & 1)] = w;
    }
  }
}

// ---------------- K3b: pure streaming apply (32-bit indexing, nt stores) ----------------
__global__ __launch_bounds__(256) void k3b_apply(const float* __restrict__ img,
                                                 const uint32_t* __restrict__ bm,
                                                 float* __restrict__ out) {
  const uint32_t tid = (uint32_t)blockIdx.x * 256u + (uint32_t)threadIdx.x; // 4096 WGs
  const float4* img4 = reinterpret_cast<const float4*>(img);
  #pragma unroll
  for (int it = 0; it < 6; ++it) {
    uint32_t f4 = (uint32_t)it * 1048576u + tid;     // 6291456 float4 total
    uint32_t q = (f4 * 4u) & (uint32_t)(kHW - 1);    // pixel index within channel
    uint32_t w = bm[q >> 5];
    uint32_t s = q & 31u;                            // multiple of 4
    float4 v = img4[f4];
    float4 o;
    o.x = ((w >> (s + 0)) & 1u) ? v.x : kGray;
    o.y = ((w >> (s + 1)) & 1u) ? v.y : kGray;
    o.z = ((w >> (s + 2)) & 1u) ? v.z : kGray;
    o.w = ((w >> (s + 3)) & 1u) ? v.w : kGray;
    nt_store4(o, out + (size_t)f4 * 4u);
  }
}

// ---------------- host ----------------
extern "C" void kernel_launch(void* const* d_in, const int* in_sizes, int n_in,
                              void* d_out, int out_size, void* d_ws, size_t ws_size,
                              hipStream_t stream) {
  const float* img   = (const float*)d_in[0];
  const float* depth = (const float*)d_in[1];
  float* out = (float*)d_out;

  // gray scratch lives in d_out (96 MiB; fully overwritten by k3b afterwards)
  float* Gu = out;                        // [kNB][4096], dropped blocks only
  float* Gs = out + kGrayN;               // second variant

  // d_ws layout (~1.04 MB, rewritten every call)
  uint32_t* bm = (uint32_t*)d_ws;         // kH*kW/32 = 262144 words
  float* S    = (float*)(bm + kHW / 32);
  float* Bmax = S + kNB;
  int*   meta = (int*)(Bmax + kNB);       // [0]=dropped count, [1]=scaled flag
  int*   list = meta + 8;                 // compact dropped-block ids (<=2048)

  uint32_t k1a, k1b_, k2a, k2b;
  tf2x32(0u, 42u, 0u, 0u, k1a, k1b_);     // split(key(42))[0]
  tf2x32(0u, 42u, 0u, 1u, k2a, k2b);      // split(key(42))[1]

  k1_depth<<<kNB, 256, 0, stream>>>(depth, Gu, Gs, Bmax, k1a, k1b_);
  k1b_meta<<<1, 256, 0, stream>>>(Bmax, meta, list, k1a, k1b_);
  kchain  <<<kNB / 2, 64, 0, stream>>>(out, meta, list, S);
  k3a_mask<<<kNB, 256, 0, stream>>>(S, bm, k1a, k1b_, k2a, k2b);
  k3b_apply<<<4096, 256, 0, stream>>>(img, bm, out);
}